// Round 2
// baseline (282.798 us; speedup 1.0000x reference)
//
#include <hip/hip_runtime.h>
#include <cstdint>

#define BATCH 64
#define NPIX 65536
#define TOPK 16384
#define NB 256          // value-uniform bins: key = floor(v*256), v in [0,1)
#define MAXCAND 1024    // expected candidates per batch ~ NPIX/NB = 256

// ---- workspace layout (bytes) ----
// gcnt : BATCH*NB u32      (65536)   } zeroed
// gsum : BATCH*NB f32      (65536)   } zeroed
// ccnt : BATCH   u32       (256)     } zeroed
// selb : BATCH   i32       (256)     } zeroed (written by K2)
// remv : BATCH   u32       (256)     } zeroed (written by K2)
// cand : BATCH*MAXCAND uint2 (524288)  no init needed
#define ZBYTES (BATCH*NB*4*2 + BATCH*4*3)

__device__ __forceinline__ void block_sum_neg_atomic(float acc, float* out) {
    __shared__ float w[4];
    #pragma unroll
    for (int off = 32; off > 0; off >>= 1) acc += __shfl_down(acc, off, 64);
    if ((threadIdx.x & 63) == 0) w[threadIdx.x >> 6] = acc;
    __syncthreads();
    if (threadIdx.x == 0) atomicAdd(out, -(w[0] + w[1] + w[2] + w[3]));
}

// llp = clamp(log(1-p)), lp = clamp(log p), p = softmax(a0,a1)[0]
__device__ __forceinline__ void bce_terms(float a0, float a1, float& lp, float& llp) {
    float m = fmaxf(a0, a1);
    float lse = m + log1pf(__expf(-fabsf(a0 - a1)));
    lp  = fmaxf(a0 - lse, -100.f);
    llp = fmaxf(a1 - lse, -100.f);
}

__device__ __forceinline__ int vkey(float v) {
    return (int)fminf(v * 256.0f, 255.0f);   // monotone bucket map for v in [0,1)
}

// ---------------------------------------------------------------------------
// K1: single pass over all data. Per-batch-segment blocks (16 blocks/batch).
// Accumulates sum(llp) into out, and per-batch 256-bin {count, sum(diff)}
// histograms (LDS first, then merged to global with atomics).
// ---------------------------------------------------------------------------
__global__ __launch_bounds__(256) void k1_hist_base(
    const float4* __restrict__ sc, const float4* __restrict__ gn,
    const float2* __restrict__ tokp,
    uint32_t* __restrict__ gcnt, float* __restrict__ gsum,
    float* __restrict__ out)
{
    __shared__ uint32_t hcnt[NB];
    __shared__ float hsum[NB];
    const int tid = threadIdx.x;
    hcnt[tid] = 0u; hsum[tid] = 0.f;
    __syncthreads();

    const int b   = blockIdx.x >> 4;     // 16 blocks per batch
    const int seg = blockIdx.x & 15;
    const int pairbase = b * (NPIX / 2) + seg * 2048;  // 2048 pairs per block
    float acc = 0.f;

    #pragma unroll
    for (int it = 0; it < 8; ++it) {
        int j = pairbase + it * 256 + tid;
        float4 s = sc[j];
        float4 g = gn[j];
        float2 tk = tokp[j];
        {
            float lp, llp; bce_terms(s.x + g.x, s.y + g.y, lp, llp);
            acc += llp;
            int k = vkey(tk.x);
            atomicAdd(&hcnt[k], 1u);
            atomicAdd(&hsum[k], lp - llp);
        }
        {
            float lp, llp; bce_terms(s.z + g.z, s.w + g.w, lp, llp);
            acc += llp;
            int k = vkey(tk.y);
            atomicAdd(&hcnt[k], 1u);
            atomicAdd(&hsum[k], lp - llp);
        }
    }
    __syncthreads();
    atomicAdd(&gcnt[b * NB + tid], hcnt[tid]);
    atomicAdd(&gsum[b * NB + tid], hsum[tid]);
    block_sum_neg_atomic(acc, out);
}

// ---------------------------------------------------------------------------
// K2: per batch, scan bins from the top; find threshold bin b1 and rem,
// add -(sum of diff over bins strictly above b1) to out.
// ---------------------------------------------------------------------------
__global__ __launch_bounds__(256) void k2_scan(
    const uint32_t* __restrict__ gcnt, const float* __restrict__ gsum,
    int* __restrict__ selb, uint32_t* __restrict__ remv, float* __restrict__ out)
{
    __shared__ uint32_t c[NB];
    __shared__ float s[NB];
    const int b = blockIdx.x, tid = threadIdx.x;
    c[tid] = gcnt[b * NB + tid];
    s[tid] = gsum[b * NB + tid];
    __syncthreads();
    if (tid == 0) {
        uint32_t cum = 0; float sa = 0.f; int bin = NB - 1; uint32_t rem = TOPK;
        for (; bin >= 0; --bin) {
            uint32_t cc = c[bin];
            if (cum + cc >= TOPK) { rem = TOPK - cum; break; }
            cum += cc; sa += s[bin];
        }
        if (bin < 0) { bin = 0; rem = TOPK - cum; }   // unreachable (N > K)
        selb[b] = bin;
        remv[b] = rem;
        atomicAdd(out, -sa);
    }
}

// ---------------------------------------------------------------------------
// K3: full scan of s_map only; compact elements whose key == b1 into
// per-batch candidate buffers (value bits + global pixel index).
// ---------------------------------------------------------------------------
__global__ __launch_bounds__(256) void k3_gather(
    const float4* __restrict__ tok4, const int* __restrict__ selb,
    uint32_t* __restrict__ ccnt, uint2* __restrict__ cand)
{
    const int tot = BATCH * NPIX / 4;
    for (int j = blockIdx.x * 256 + threadIdx.x; j < tot; j += gridDim.x * 256) {
        float4 v = tok4[j];
        int px = j * 4;
        int b = px >> 16;               // NPIX = 65536, 4-aligned so same batch
        int sb = selb[b];
        float fv[4] = {v.x, v.y, v.z, v.w};
        #pragma unroll
        for (int q = 0; q < 4; ++q) {
            if (vkey(fv[q]) == sb) {
                uint32_t pos = atomicAdd(&ccnt[b], 1u);
                if (pos < MAXCAND)
                    cand[b * MAXCAND + pos] =
                        make_uint2(__float_as_uint(fv[q]), (uint32_t)(px + q));
            }
        }
    }
}

// ---------------------------------------------------------------------------
// K4: per batch, exact rank of each candidate under (value desc, index asc)
// -- lax.top_k tie semantics. Selected (rank < rem) candidates contribute
// diff = lp - llp, recomputed from scores+gumbel.
// ---------------------------------------------------------------------------
__global__ __launch_bounds__(256) void k4_finalize(
    const uint2* __restrict__ cand, const uint32_t* __restrict__ ccnt,
    const uint32_t* __restrict__ remv,
    const float2* __restrict__ sc2, const float2* __restrict__ gn2,
    float* __restrict__ out)
{
    __shared__ uint32_t vb[MAXCAND];
    __shared__ uint32_t vi[MAXCAND];
    const int b = blockIdx.x, tid = threadIdx.x;
    const uint32_t cnt = min(ccnt[b], (uint32_t)MAXCAND);
    const uint32_t rem = remv[b];
    for (uint32_t j = tid; j < cnt; j += 256) {
        uint2 e = cand[b * MAXCAND + j];
        vb[j] = e.x; vi[j] = e.y;
    }
    __syncthreads();
    float acc = 0.f;
    for (uint32_t j = tid; j < cnt; j += 256) {
        const uint32_t mb = vb[j], mi = vi[j];
        uint32_t rank = 0;
        for (uint32_t i = 0; i < cnt; ++i) {
            uint32_t ob = vb[i];
            rank += (ob > mb) || (ob == mb && vi[i] < mi);
        }
        if (rank < rem) {
            float2 s = sc2[mi];
            float2 g = gn2[mi];
            float lp, llp; bce_terms(s.x + g.x, s.y + g.y, lp, llp);
            acc += lp - llp;
        }
    }
    block_sum_neg_atomic(acc, out);
}

extern "C" void kernel_launch(void* const* d_in, const int* in_sizes, int n_in,
                              void* d_out, int out_size, void* d_ws, size_t ws_size,
                              hipStream_t stream) {
    const float* scores = (const float*)d_in[0];   // [B, N, 2]
    const float* smap   = (const float*)d_in[1];   // [B, N]
    const float* gumbel = (const float*)d_in[2];   // [B, N, 2]
    float* out = (float*)d_out;

    char* ws = (char*)d_ws;
    uint32_t* gcnt = (uint32_t*)ws;                    ws += BATCH * NB * 4;
    float*    gsum = (float*)ws;                       ws += BATCH * NB * 4;
    uint32_t* ccnt = (uint32_t*)ws;                    ws += BATCH * 4;
    int*      selb = (int*)ws;                         ws += BATCH * 4;
    uint32_t* remv = (uint32_t*)ws;                    ws += BATCH * 4;
    uint2*    cand = (uint2*)ws;

    hipMemsetAsync(d_ws, 0, ZBYTES, stream);
    hipMemsetAsync(out, 0, sizeof(float), stream);

    k1_hist_base<<<1024, 256, 0, stream>>>(
        (const float4*)scores, (const float4*)gumbel, (const float2*)smap,
        gcnt, gsum, out);

    k2_scan<<<BATCH, 256, 0, stream>>>(gcnt, gsum, selb, remv, out);

    k3_gather<<<1024, 256, 0, stream>>>((const float4*)smap, selb, ccnt, cand);

    k4_finalize<<<BATCH, 256, 0, stream>>>(
        cand, ccnt, remv, (const float2*)scores, (const float2*)gumbel, out);
}

// Round 3
// 149.041 us; speedup vs baseline: 1.8974x; 1.8974x over previous
//
#include <hip/hip_runtime.h>
#include <cstdint>

#define BATCH 64
#define NPIX 65536
#define TOPK 16384
#define NB 256          // value-uniform bins: key = floor(v*256), v in [0,1)
#define MAXCAND 1024    // candidates per batch kept for exact tie-break (~256 expected)
#define CCNT_STRIDE 32  // u32 stride per batch counter -> 128B, no line sharing
#define LBUF 512        // per-block LDS candidate capacity (expected ~16)

__device__ __forceinline__ float block_reduce(float acc) {
    __shared__ float w[4];
    #pragma unroll
    for (int off = 32; off > 0; off >>= 1) acc += __shfl_down(acc, off, 64);
    if ((threadIdx.x & 63) == 0) w[threadIdx.x >> 6] = acc;
    __syncthreads();
    return w[0] + w[1] + w[2] + w[3];
}

// lp = clamp(log p), llp = clamp(log(1-p)), p = softmax(a0,a1)[0]
__device__ __forceinline__ void bce_terms(float a0, float a1, float& lp, float& llp) {
    float m = fmaxf(a0, a1);
    float lse = m + log1pf(__expf(-fabsf(a0 - a1)));
    lp  = fmaxf(a0 - lse, -100.f);
    llp = fmaxf(a1 - lse, -100.f);
}

__device__ __forceinline__ int vkey(float v) {
    return (int)fminf(v * 256.0f, 255.0f);   // monotone bucket map, v in [0,1)
}

// ---------------------------------------------------------------------------
// K1: single pass over all 80MB. 16 blocks/batch. Per-block sum(llp) -> pk1
// (plain store, no atomics). Per-batch 256-bin {count, sum(lp-llp)} hist:
// LDS first, then low-contention global atomic merge (<=16 per address).
// ---------------------------------------------------------------------------
__global__ __launch_bounds__(256) void k1_hist_base(
    const float4* __restrict__ sc, const float4* __restrict__ gn,
    const float2* __restrict__ tokp,
    uint32_t* __restrict__ gcnt, float* __restrict__ gsum,
    float* __restrict__ pk1)
{
    __shared__ uint32_t hcnt[NB];
    __shared__ float hsum[NB];
    const int tid = threadIdx.x;
    hcnt[tid] = 0u; hsum[tid] = 0.f;
    __syncthreads();

    const int b   = blockIdx.x >> 4;
    const int seg = blockIdx.x & 15;
    const int pairbase = b * (NPIX / 2) + seg * 2048;  // 2048 float4-pairs/block
    float acc = 0.f;

    #pragma unroll
    for (int it = 0; it < 8; ++it) {
        int j = pairbase + it * 256 + tid;
        float4 s = sc[j];
        float4 g = gn[j];
        float2 tk = tokp[j];
        {
            float lp, llp; bce_terms(s.x + g.x, s.y + g.y, lp, llp);
            acc += llp;
            int k = vkey(tk.x);
            atomicAdd(&hcnt[k], 1u);
            atomicAdd(&hsum[k], lp - llp);
        }
        {
            float lp, llp; bce_terms(s.z + g.z, s.w + g.w, lp, llp);
            acc += llp;
            int k = vkey(tk.y);
            atomicAdd(&hcnt[k], 1u);
            atomicAdd(&hsum[k], lp - llp);
        }
    }
    __syncthreads();
    atomicAdd(&gcnt[b * NB + tid], hcnt[tid]);
    atomicAdd(&gsum[b * NB + tid], hsum[tid]);
    float tot = block_reduce(acc);
    if (tid == 0) pk1[blockIdx.x] = tot;
}

// ---------------------------------------------------------------------------
// K2: per batch, top-down bin scan -> threshold bin, remainder, and the
// sum(diff) over bins strictly above. Plain stores only.
// ---------------------------------------------------------------------------
__global__ __launch_bounds__(256) void k2_scan(
    const uint32_t* __restrict__ gcnt, const float* __restrict__ gsum,
    int* __restrict__ selb, uint32_t* __restrict__ remv, float* __restrict__ pk2)
{
    __shared__ uint32_t c[NB];
    __shared__ float s[NB];
    const int b = blockIdx.x, tid = threadIdx.x;
    c[tid] = gcnt[b * NB + tid];
    s[tid] = gsum[b * NB + tid];
    __syncthreads();
    if (tid == 0) {
        uint32_t cum = 0; float sa = 0.f; int bin = NB - 1; uint32_t rem = TOPK;
        for (; bin >= 0; --bin) {
            uint32_t cc = c[bin];
            if (cum + cc >= TOPK) { rem = TOPK - cum; break; }
            cum += cc; sa += s[bin];
        }
        if (bin < 0) { bin = 0; rem = TOPK - cum; }   // unreachable (N > K)
        selb[b] = bin;
        remv[b] = rem;
        pk2[b] = sa;
    }
}

// ---------------------------------------------------------------------------
// K3: batch-aligned re-scan of s_map (L3-hot). Per-block LDS compaction of
// threshold-bin hits; ONE global atomic per block on a 128B-padded counter.
// ---------------------------------------------------------------------------
__global__ __launch_bounds__(256) void k3_gather(
    const float4* __restrict__ tok4, const int* __restrict__ selb,
    uint32_t* __restrict__ ccnt, uint2* __restrict__ cand)
{
    __shared__ uint2 lbuf[LBUF];
    __shared__ uint32_t lcnt, lbase;
    const int tid = threadIdx.x;
    if (tid == 0) lcnt = 0;
    __syncthreads();

    const int b   = blockIdx.x >> 4;
    const int seg = blockIdx.x & 15;
    const int base4 = b * (NPIX / 4) + seg * 1024;   // 4096 px per block
    const int sb = selb[b];

    #pragma unroll
    for (int it = 0; it < 4; ++it) {
        int j = base4 + it * 256 + tid;
        float4 v = tok4[j];
        int px = j * 4;                               // global pixel index
        float fv[4] = {v.x, v.y, v.z, v.w};
        #pragma unroll
        for (int q = 0; q < 4; ++q) {
            if (vkey(fv[q]) == sb) {
                uint32_t p = atomicAdd(&lcnt, 1u);
                if (p < LBUF)
                    lbuf[p] = make_uint2(__float_as_uint(fv[q]), (uint32_t)(px + q));
            }
        }
    }
    __syncthreads();
    uint32_t n = min(lcnt, (uint32_t)LBUF);
    if (tid == 0) lbase = atomicAdd(&ccnt[b * CCNT_STRIDE], n);
    __syncthreads();
    uint32_t bs = lbase;
    for (uint32_t j = tid; j < n; j += 256) {
        uint32_t pos = bs + j;
        if (pos < MAXCAND) cand[b * MAXCAND + pos] = lbuf[j];
    }
}

// ---------------------------------------------------------------------------
// K4: per batch, exact rank under (value desc, index asc) == lax.top_k tie
// semantics; selected candidates contribute diff = lp - llp. Plain store.
// ---------------------------------------------------------------------------
__global__ __launch_bounds__(256) void k4_finalize(
    const uint2* __restrict__ cand, const uint32_t* __restrict__ ccnt,
    const uint32_t* __restrict__ remv,
    const float2* __restrict__ sc2, const float2* __restrict__ gn2,
    float* __restrict__ pk4)
{
    __shared__ uint32_t vb[MAXCAND];
    __shared__ uint32_t vi[MAXCAND];
    const int b = blockIdx.x, tid = threadIdx.x;
    const uint32_t cnt = min(ccnt[b * CCNT_STRIDE], (uint32_t)MAXCAND);
    const uint32_t rem = remv[b];
    for (uint32_t j = tid; j < cnt; j += 256) {
        uint2 e = cand[b * MAXCAND + j];
        vb[j] = e.x; vi[j] = e.y;
    }
    __syncthreads();
    float acc = 0.f;
    for (uint32_t j = tid; j < cnt; j += 256) {
        const uint32_t mb = vb[j], mi = vi[j];
        uint32_t rank = 0;
        for (uint32_t i = 0; i < cnt; ++i) {
            uint32_t ob = vb[i];
            rank += (ob > mb) || (ob == mb && vi[i] < mi);
        }
        if (rank < rem) {
            float2 s = sc2[mi];
            float2 g = gn2[mi];
            float lp, llp; bce_terms(s.x + g.x, s.y + g.y, lp, llp);
            acc += lp - llp;
        }
    }
    float tot = block_reduce(acc);
    if (tid == 0) pk4[b] = tot;
}

// ---------------------------------------------------------------------------
// K5: sum the 1152 partials, write out = -(total). Single block.
// ---------------------------------------------------------------------------
__global__ __launch_bounds__(256) void k5_reduce(
    const float* __restrict__ parts, float* __restrict__ out)
{
    float acc = 0.f;
    for (int i = threadIdx.x; i < 1024 + BATCH + BATCH; i += 256) acc += parts[i];
    float tot = block_reduce(acc);
    if (threadIdx.x == 0) out[0] = -tot;
}

extern "C" void kernel_launch(void* const* d_in, const int* in_sizes, int n_in,
                              void* d_out, int out_size, void* d_ws, size_t ws_size,
                              hipStream_t stream) {
    const float* scores = (const float*)d_in[0];   // [B, N, 2]
    const float* smap   = (const float*)d_in[1];   // [B, N]
    const float* gumbel = (const float*)d_in[2];   // [B, N, 2]
    float* out = (float*)d_out;

    // ---- workspace layout ----
    char* ws = (char*)d_ws;
    uint32_t* gcnt = (uint32_t*)ws;            ws += BATCH * NB * 4;          // zeroed
    float*    gsum = (float*)ws;               ws += BATCH * NB * 4;          // zeroed
    uint32_t* ccnt = (uint32_t*)ws;            ws += BATCH * CCNT_STRIDE * 4; // zeroed
    const size_t zbytes = (size_t)((char*)ws - (char*)d_ws);
    int*      selb = (int*)ws;                 ws += BATCH * 4;
    uint32_t* remv = (uint32_t*)ws;            ws += BATCH * 4;
    float*    pall = (float*)ws;               ws += (1024 + BATCH + BATCH) * 4;
    float*    pk1  = pall;
    float*    pk2  = pall + 1024;
    float*    pk4  = pall + 1024 + BATCH;
    uint2*    cand = (uint2*)ws;

    hipMemsetAsync(d_ws, 0, zbytes, stream);

    k1_hist_base<<<1024, 256, 0, stream>>>(
        (const float4*)scores, (const float4*)gumbel, (const float2*)smap,
        gcnt, gsum, pk1);

    k2_scan<<<BATCH, 256, 0, stream>>>(gcnt, gsum, selb, remv, pk2);

    k3_gather<<<1024, 256, 0, stream>>>((const float4*)smap, selb, ccnt, cand);

    k4_finalize<<<BATCH, 256, 0, stream>>>(
        cand, ccnt, remv, (const float2*)scores, (const float2*)gumbel, pk4);

    k5_reduce<<<1, 256, 0, stream>>>(pall, out);
}